// Round 1
// baseline (1894.514 us; speedup 1.0000x reference)
//
#include <hip/hip_runtime.h>
#include <cstdint>
#include <cstddef>

#define N_IN    32
#define N_HID   200
#define N_OUT   3
#define FAN_IN  232   // N_IN + N_HID
#define T_STEPS 2000
#define BLOCK   256
#define NW      4     // waves per block

__device__ __forceinline__ float sigmoidf_(float v) {
    return 1.0f / (1.0f + expf(-v));
}

// Load 32 fp32 x-values for one timestep (wave-uniform address -> s_load)
#define LOADX(DST, T_)                                              \
    {                                                               \
        const float* xp_ = xrow + (size_t)(T_) * N_IN;              \
        _Pragma("unroll")                                           \
        for (int j_ = 0; j_ < N_IN; ++j_) DST[j_] = xp_[j_];        \
    }

// One recurrence step. XV: registers holding x_t. TCUR: timestep (for t>0
// accumulation guard). PREF_COND/PREF_DST/PREF_T: prefetch of next x row,
// issued before the barrier so latency overlaps barrier+readout.
#define STEP(XV, TCUR, PREF_COND, PREF_DST, PREF_T)                               \
    {                                                                             \
        float c0 = bias, c1 = 0.f, c2 = 0.f, c3 = 0.f;                            \
        _Pragma("unroll")                                                         \
        for (int j = 0; j < N_IN; j += 4) {                                       \
            c0 = fmaf(XV[j + 0], wx[j + 0], c0);                                  \
            c1 = fmaf(XV[j + 1], wx[j + 1], c1);                                  \
            c2 = fmaf(XV[j + 2], wx[j + 2], c2);                                  \
            c3 = fmaf(XV[j + 3], wx[j + 3], c3);                                  \
        }                                                                         \
        float cur = (c0 + c1) + (c2 + c3);                                        \
        _Pragma("unroll")                                                         \
        for (int w = 0; w < NW; ++w) {                                            \
            unsigned long long m_ = smask[p][w];                                  \
            while (m_) {                                                          \
                int j = (w << 6) + __builtin_ctzll(m_);                           \
                m_ &= m_ - 1;                                                     \
                cur += wrow[N_IN + j] * mrow[N_IN + j];                           \
            }                                                                     \
        }                                                                         \
        dcur = fmaf(beta, dcur, omb * cur);                                       \
        mem1 = fmaf(a1, mem1, fmaf(oma1, dcur, -sprev));                          \
        float snew = (mem1 > 1.0f) ? 1.0f : 0.0f;                                 \
        sprev = snew;                                                             \
        unsigned long long bal = __ballot(active && (snew > 0.5f));               \
        if (lane == 0) smask[p ^ 1][wid] = bal;                                   \
        if (PREF_COND) LOADX(PREF_DST, PREF_T);                                   \
        __syncthreads();                                                          \
        if (tid < N_OUT) {                                                        \
            float r = b2v;                                                        \
            _Pragma("unroll")                                                     \
            for (int w = 0; w < NW; ++w) {                                        \
                unsigned long long m_ = smask[p ^ 1][w];                          \
                while (m_) {                                                      \
                    int j = (w << 6) + __builtin_ctzll(m_);                       \
                    m_ &= m_ - 1;                                                 \
                    r += W2L[tid * N_HID + j];                                    \
                }                                                                 \
            }                                                                     \
            mem2 = fmaf(a2, mem2, oma2 * r);                                      \
            if ((TCUR) > 0) acc += mem2;                                          \
        }                                                                         \
        p ^= 1;                                                                   \
    }

__global__ __launch_bounds__(BLOCK, 2) void dhsnn_dense_kernel(
    const float* __restrict__ x,       // [B, T, N_IN]
    const float* __restrict__ W1,      // [N_HID, FAN_IN]
    const float* __restrict__ b1,      // [N_HID]
    const float* __restrict__ tau_n,   // [N_HID, 1]
    const float* __restrict__ tau_m1,  // [N_HID]
    const float* __restrict__ W2,      // [N_OUT, N_HID]
    const float* __restrict__ b2,      // [N_OUT]
    const float* __restrict__ tau_m2,  // [N_OUT]
    const float* __restrict__ mask,    // [N_HID, FAN_IN] (all ones here)
    float* __restrict__ out)           // [B, N_OUT]
{
    const int b    = blockIdx.x;
    const int tid  = threadIdx.x;
    const int wid  = tid >> 6;
    const int lane = tid & 63;
    const bool active = (tid < N_HID);
    const int hc = active ? tid : (N_HID - 1);

    __shared__ float W2L[N_OUT * N_HID];
    __shared__ unsigned long long smask[2][NW];

    for (int i = tid; i < N_OUT * N_HID; i += BLOCK) W2L[i] = W2[i];
    if (tid < 2 * NW) ((unsigned long long*)smask)[tid] = 0ull;

    // Per-neuron parameters (masked input weights in registers)
    const float* wrow = W1 + (size_t)hc * FAN_IN;
    const float* mrow = mask + (size_t)hc * FAN_IN;
    float wx[N_IN];
#pragma unroll
    for (int j = 0; j < N_IN; ++j) wx[j] = wrow[j] * mrow[j];
    const float bias = b1[hc];
    const float beta = sigmoidf_(tau_n[hc]);    // branch = 1
    const float a1   = sigmoidf_(tau_m1[hc]);
    const float omb  = 1.0f - beta;
    const float oma1 = 1.0f - a1;

    // Recurrent state
    float dcur = 0.f, mem1 = 0.f, sprev = 0.f;

    // Readout state (threads 0..2 each own one output)
    float a2 = 0.f, oma2 = 0.f, b2v = 0.f, mem2 = 0.f, acc = 0.f;
    if (tid < N_OUT) {
        a2   = sigmoidf_(tau_m2[tid]);
        oma2 = 1.0f - a2;
        b2v  = b2[tid];
    }

    const float* xrow = x + (size_t)b * T_STEPS * N_IN;

    float xa[N_IN], xb[N_IN];
    LOADX(xa, 0);

    __syncthreads();

    int p = 0;
    for (int t = 0; t < T_STEPS; t += 2) {
        STEP(xa, t, true, xb, t + 1);
        STEP(xb, t + 1, (t + 2 < T_STEPS), xa, t + 2);
    }

    if (tid < N_OUT) out[(size_t)b * N_OUT + tid] = acc / (float)T_STEPS;
}

extern "C" void kernel_launch(void* const* d_in, const int* in_sizes, int n_in,
                              void* d_out, int out_size, void* d_ws, size_t ws_size,
                              hipStream_t stream) {
    const float* x      = (const float*)d_in[0];
    const float* W1     = (const float*)d_in[1];
    const float* b1     = (const float*)d_in[2];
    const float* tau_n  = (const float*)d_in[3];
    const float* tau_m1 = (const float*)d_in[4];
    const float* W2     = (const float*)d_in[5];
    const float* b2     = (const float*)d_in[6];
    const float* tau_m2 = (const float*)d_in[7];
    const float* mask   = (const float*)d_in[8];
    float* out = (float*)d_out;

    const int B = in_sizes[0] / (T_STEPS * N_IN);  // 512

    hipLaunchKernelGGL(dhsnn_dense_kernel, dim3(B), dim3(BLOCK), 0, stream,
                       x, W1, b1, tau_n, tau_m1, W2, b2, tau_m2, mask, out);
}

// Round 2
// 1429.101 us; speedup vs baseline: 1.3257x; 1.3257x over previous
//
#include <hip/hip_runtime.h>
#include <cstdint>
#include <cstddef>

#define N_IN    32
#define N_HID   200
#define N_OUT   3
#define FAN_IN  232   // N_IN + N_HID
#define T_STEPS 2000
#define BLOCK   256
#define NW      4     // waves per block

#define CHUNK     40                    // timesteps staged per LDS buffer
#define NCHUNK    (T_STEPS / CHUNK)     // 50, exact
#define XS_FLOATS (CHUNK * N_IN)        // 1280 floats per buffer
#define GXN       (XS_FLOATS / BLOCK)   // 5 floats per thread per chunk

__device__ __forceinline__ float sigmoidf_(float v) {
    return 1.0f / (1.0f + expf(-v));
}

// Load one timestep's 32 x-values from LDS (uniform address -> broadcast)
#define LOADX_LDS(DST, BUF, S)                                      \
    {                                                               \
        const float* xp_ = &xs[BUF][(S) * N_IN];                    \
        _Pragma("unroll")                                           \
        for (int j_ = 0; j_ < N_IN; ++j_) DST[j_] = xp_[j_];        \
    }

#define COMPUTE_AND_BALLOT(XV)                                                    \
        float c0 = bias, c1 = 0.f, c2 = 0.f, c3 = 0.f;                            \
        _Pragma("unroll")                                                         \
        for (int j = 0; j < N_IN; j += 4) {                                       \
            c0 = fmaf(XV[j + 0], wx[j + 0], c0);                                  \
            c1 = fmaf(XV[j + 1], wx[j + 1], c1);                                  \
            c2 = fmaf(XV[j + 2], wx[j + 2], c2);                                  \
            c3 = fmaf(XV[j + 3], wx[j + 3], c3);                                  \
        }                                                                         \
        float cur = (c0 + c1) + (c2 + c3);                                        \
        _Pragma("unroll")                                                         \
        for (int w = 0; w < NW; ++w) {                                            \
            unsigned long long m_ = smask[p][w];                                  \
            while (m_) {                                                          \
                int j = (w << 6) + __builtin_ctzll(m_);                           \
                m_ &= m_ - 1;                                                     \
                cur += wrow[N_IN + j] * mrow[N_IN + j];                           \
            }                                                                     \
        }                                                                         \
        dcur = fmaf(beta, dcur, omb * cur);                                       \
        mem1 = fmaf(a1, mem1, fmaf(oma1, dcur, -sprev));                          \
        float snew = (mem1 > 1.0f) ? 1.0f : 0.0f;                                 \
        sprev = snew;                                                             \
        unsigned long long bal = __ballot(active && (snew > 0.5f));               \
        if (lane == 0) smask[p ^ 1][wid] = bal;

#define READOUT(TCUR)                                                             \
        if (tid < N_OUT) {                                                        \
            float r = b2v;                                                        \
            _Pragma("unroll")                                                     \
            for (int w = 0; w < NW; ++w) {                                        \
                unsigned long long m_ = smask[p ^ 1][w];                          \
                while (m_) {                                                      \
                    int j = (w << 6) + __builtin_ctzll(m_);                       \
                    m_ &= m_ - 1;                                                 \
                    r += W2L[tid * N_HID + j];                                    \
                }                                                                 \
            }                                                                     \
            mem2 = fmaf(a2, mem2, oma2 * r);                                      \
            if ((TCUR) > 0) acc += mem2;                                          \
        }

// Normal step: compute, ballot, prefetch next x row from LDS, barrier, readout.
#define STEP(XV, TCUR, PREF_DST, PBUF, PS)                                        \
    {                                                                             \
        COMPUTE_AND_BALLOT(XV)                                                    \
        LOADX_LDS(PREF_DST, PBUF, PS);                                            \
        __syncthreads();                                                          \
        READOUT(TCUR)                                                             \
        p ^= 1;                                                                   \
    }

__global__ __launch_bounds__(BLOCK, 2) void dhsnn_dense_kernel(
    const float* __restrict__ x,       // [B, T, N_IN]
    const float* __restrict__ W1,      // [N_HID, FAN_IN]
    const float* __restrict__ b1,      // [N_HID]
    const float* __restrict__ tau_n,   // [N_HID, 1]
    const float* __restrict__ tau_m1,  // [N_HID]
    const float* __restrict__ W2,      // [N_OUT, N_HID]
    const float* __restrict__ b2,      // [N_OUT]
    const float* __restrict__ tau_m2,  // [N_OUT]
    const float* __restrict__ mask,    // [N_HID, FAN_IN] (all ones here)
    float* __restrict__ out)           // [B, N_OUT]
{
    const int b    = blockIdx.x;
    const int tid  = threadIdx.x;
    const int wid  = tid >> 6;
    const int lane = tid & 63;
    const bool active = (tid < N_HID);
    const int hc = active ? tid : (N_HID - 1);

    __shared__ float W2L[N_OUT * N_HID];
    __shared__ unsigned long long smask[2][NW];
    __shared__ float xs[2][XS_FLOATS];

    for (int i = tid; i < N_OUT * N_HID; i += BLOCK) W2L[i] = W2[i];
    if (tid < 2 * NW) ((unsigned long long*)smask)[tid] = 0ull;

    // Per-neuron parameters (masked input weights in registers)
    const float* wrow = W1 + (size_t)hc * FAN_IN;
    const float* mrow = mask + (size_t)hc * FAN_IN;
    float wx[N_IN];
#pragma unroll
    for (int j = 0; j < N_IN; ++j) wx[j] = wrow[j] * mrow[j];
    const float bias = b1[hc];
    const float beta = sigmoidf_(tau_n[hc]);    // branch = 1
    const float a1   = sigmoidf_(tau_m1[hc]);
    const float omb  = 1.0f - beta;
    const float oma1 = 1.0f - a1;

    // Recurrent state
    float dcur = 0.f, mem1 = 0.f, sprev = 0.f;

    // Readout state (threads 0..2 each own one output)
    float a2 = 0.f, oma2 = 0.f, b2v = 0.f, mem2 = 0.f, acc = 0.f;
    if (tid < N_OUT) {
        a2   = sigmoidf_(tau_m2[tid]);
        oma2 = 1.0f - a2;
        b2v  = b2[tid];
    }

    const float* xrow = x + (size_t)b * T_STEPS * N_IN;

    // --- Prologue: chunk 0 -> LDS, issue chunk 1 into registers ---
    float gx[GXN];
#pragma unroll
    for (int k = 0; k < GXN; ++k) gx[k] = xrow[tid + k * BLOCK];
#pragma unroll
    for (int k = 0; k < GXN; ++k) xs[0][tid + k * BLOCK] = gx[k];
#pragma unroll
    for (int k = 0; k < GXN; ++k) gx[k] = xrow[XS_FLOATS + tid + k * BLOCK];

    __syncthreads();

    float xa[N_IN], xb[N_IN];
    LOADX_LDS(xa, 0, 0);

    int p = 0;
    for (int c = 0; c < NCHUNK; ++c) {
        const int buf = c & 1;
        const int t0 = c * CHUNK;
#pragma unroll 1
        for (int s = 0; s < CHUNK - 2; s += 2) {
            STEP(xa, t0 + s,     xb, buf, s + 1);
            STEP(xb, t0 + s + 1, xa, buf, s + 2);
        }
        STEP(xa, t0 + CHUNK - 2, xb, buf, CHUNK - 1);
        // Last step of chunk: write next chunk to LDS, then refill gx and xa.
        {
            COMPUTE_AND_BALLOT(xb)
            if (c < NCHUNK - 1) {
#pragma unroll
                for (int k = 0; k < GXN; ++k) xs[buf ^ 1][tid + k * BLOCK] = gx[k];
            }
            __syncthreads();
            READOUT(t0 + CHUNK - 1)
            if (c < NCHUNK - 2) {
#pragma unroll
                for (int k = 0; k < GXN; ++k)
                    gx[k] = xrow[(size_t)(c + 2) * XS_FLOATS + tid + k * BLOCK];
            }
            if (c < NCHUNK - 1) LOADX_LDS(xa, buf ^ 1, 0);
            p ^= 1;
        }
    }

    if (tid < N_OUT) out[(size_t)b * N_OUT + tid] = acc / (float)T_STEPS;
}

extern "C" void kernel_launch(void* const* d_in, const int* in_sizes, int n_in,
                              void* d_out, int out_size, void* d_ws, size_t ws_size,
                              hipStream_t stream) {
    const float* x      = (const float*)d_in[0];
    const float* W1     = (const float*)d_in[1];
    const float* b1     = (const float*)d_in[2];
    const float* tau_n  = (const float*)d_in[3];
    const float* tau_m1 = (const float*)d_in[4];
    const float* W2     = (const float*)d_in[5];
    const float* b2     = (const float*)d_in[6];
    const float* tau_m2 = (const float*)d_in[7];
    const float* mask   = (const float*)d_in[8];
    float* out = (float*)d_out;

    const int B = in_sizes[0] / (T_STEPS * N_IN);  // 512

    hipLaunchKernelGGL(dhsnn_dense_kernel, dim3(B), dim3(BLOCK), 0, stream,
                       x, W1, b1, tau_n, tau_m1, W2, b2, tau_m2, mask, out);
}

// Round 3
// 864.406 us; speedup vs baseline: 2.1917x; 1.6533x over previous
//
#include <hip/hip_runtime.h>
#include <cstdint>
#include <cstddef>

#define N_IN    32
#define N_HID   200
#define N_OUT   3
#define FAN_IN  232   // N_IN + N_HID
#define T_STEPS 2000
#define WAVE    64
#define NSLOT   4     // neuron slots per lane: 64*4 = 256 >= 200

#define CHUNK   40                    // timesteps per LDS buffer
#define NCHUNK  (T_STEPS / CHUNK)     // 50, exact
#define XS_F4   (CHUNK * N_IN / 4)    // 320 float4 per buffer
#define GXK     (XS_F4 / WAVE)        // 5 float4 per lane per chunk

__device__ __forceinline__ float sigmoidf_(float v) {
    return 1.0f / (1.0f + expf(-v));
}

// Broadcast-read one timestep's 32 x values from LDS (uniform address).
#define LOADX(DST, BUF, S)                                                        \
    {                                                                             \
        const float4* xp4_ = reinterpret_cast<const float4*>(&xs[BUF][(S) * N_IN]); \
        _Pragma("unroll")                                                         \
        for (int q_ = 0; q_ < N_IN / 4; ++q_) {                                   \
            float4 v_ = xp4_[q_];                                                 \
            DST[4*q_+0] = v_.x; DST[4*q_+1] = v_.y;                               \
            DST[4*q_+2] = v_.z; DST[4*q_+3] = v_.w;                               \
        }                                                                         \
    }

// One recurrence step for 4 neuron slots. Reads spike masks sm0..sm3 (t-1),
// overwrites them with this step's spikes. No barriers anywhere.
#define STEP_CORE(XV)                                                             \
    {                                                                             \
        float cur[NSLOT];                                                         \
        _Pragma("unroll")                                                         \
        for (int s_ = 0; s_ < NSLOT; ++s_) {                                      \
            float c0 = bias[s_], c1 = 0.f, c2 = 0.f, c3 = 0.f;                    \
            _Pragma("unroll")                                                     \
            for (int j_ = 0; j_ < N_IN; j_ += 4) {                                \
                c0 = fmaf(XV[j_ + 0], wx[s_][j_ + 0], c0);                        \
                c1 = fmaf(XV[j_ + 1], wx[s_][j_ + 1], c1);                        \
                c2 = fmaf(XV[j_ + 2], wx[s_][j_ + 2], c2);                        \
                c3 = fmaf(XV[j_ + 3], wx[s_][j_ + 3], c3);                        \
            }                                                                     \
            cur[s_] = (c0 + c1) + (c2 + c3);                                      \
        }                                                                         \
        if (sm0 | sm1 | sm2 | sm3) {   /* recurrent input: rare */                \
            unsigned long long mm_[NSLOT] = {sm0, sm1, sm2, sm3};                 \
            _Pragma("unroll")                                                     \
            for (int ss_ = 0; ss_ < NSLOT; ++ss_) {                               \
                unsigned long long m_ = mm_[ss_];                                 \
                while (m_) {                                                      \
                    int j_ = (ss_ << 6) + __builtin_ctzll(m_);                    \
                    m_ &= m_ - 1;                                                 \
                    _Pragma("unroll")                                             \
                    for (int s_ = 0; s_ < NSLOT; ++s_) {                          \
                        size_t o_ = (size_t)hc[s_] * FAN_IN + N_IN + j_;          \
                        cur[s_] += W1[o_] * mask[o_];                             \
                    }                                                             \
                }                                                                 \
            }                                                                     \
        }                                                                         \
        _Pragma("unroll")                                                         \
        for (int s_ = 0; s_ < NSLOT; ++s_) {                                      \
            dcur[s_] = fmaf(beta[s_], dcur[s_], omb[s_] * cur[s_]);               \
            mem1[s_] = fmaf(a1[s_], mem1[s_], fmaf(oma1[s_], dcur[s_], -sprev[s_])); \
            sprev[s_] = (mem1[s_] > 1.0f) ? 1.0f : 0.0f;                          \
        }                                                                         \
        sm0 = __ballot(mem1[0] > 1.0f);                                           \
        sm1 = __ballot(mem1[1] > 1.0f);                                           \
        sm2 = __ballot(mem1[2] > 1.0f);                                           \
        sm3 = __ballot(mem1[3] > 1.0f) & 0xFFull;  /* neurons 192..199 only */    \
    }

// Leaky readout on lanes 0..2, using THIS step's spikes (sm*).
#define READOUT(TCUR)                                                             \
    {                                                                             \
        if (lane < N_OUT) {                                                       \
            float r_ = b2v;                                                       \
            if (sm0 | sm1 | sm2 | sm3) {                                          \
                unsigned long long mm_[NSLOT] = {sm0, sm1, sm2, sm3};             \
                _Pragma("unroll")                                                 \
                for (int ss_ = 0; ss_ < NSLOT; ++ss_) {                           \
                    unsigned long long m_ = mm_[ss_];                             \
                    while (m_) {                                                  \
                        int j_ = (ss_ << 6) + __builtin_ctzll(m_);                \
                        m_ &= m_ - 1;                                             \
                        r_ += W2L[lane * N_HID + j_];                             \
                    }                                                             \
                }                                                                 \
            }                                                                     \
            mem2 = fmaf(a2, mem2, oma2 * r_);                                     \
            if ((TCUR) > 0) acc += mem2;                                          \
        }                                                                         \
    }

__global__ __launch_bounds__(WAVE, 1) void dhsnn_wave_kernel(
    const float* __restrict__ x,       // [B, T, N_IN]
    const float* __restrict__ W1,      // [N_HID, FAN_IN]
    const float* __restrict__ b1,      // [N_HID]
    const float* __restrict__ tau_n,   // [N_HID, 1]
    const float* __restrict__ tau_m1,  // [N_HID]
    const float* __restrict__ W2,      // [N_OUT, N_HID]
    const float* __restrict__ b2,      // [N_OUT]
    const float* __restrict__ tau_m2,  // [N_OUT]
    const float* __restrict__ mask,    // [N_HID, FAN_IN]
    float* __restrict__ out)           // [B, N_OUT]
{
    const int b    = blockIdx.x;
    const int lane = threadIdx.x;      // single wave per block

    __shared__ float W2L[N_OUT * N_HID];        // 2.4 KB
    __shared__ float xs[2][CHUNK * N_IN];       // 10 KB

    for (int i = lane; i < N_OUT * N_HID; i += WAVE) W2L[i] = W2[i];

    // Per-slot neuron parameters (input weights masked, in registers)
    int   hc[NSLOT];
    float wx[NSLOT][N_IN];
    float bias[NSLOT], beta[NSLOT], a1[NSLOT], omb[NSLOT], oma1[NSLOT];
#pragma unroll
    for (int s = 0; s < NSLOT; ++s) {
        int h = s * WAVE + lane;
        hc[s] = (h < N_HID) ? h : (N_HID - 1);
        const float* wr = W1  + (size_t)hc[s] * FAN_IN;
        const float* mr = mask + (size_t)hc[s] * FAN_IN;
#pragma unroll
        for (int j = 0; j < N_IN; ++j) wx[s][j] = wr[j] * mr[j];
        bias[s] = b1[hc[s]];
        beta[s] = sigmoidf_(tau_n[hc[s]]);
        a1[s]   = sigmoidf_(tau_m1[hc[s]]);
        omb[s]  = 1.0f - beta[s];
        oma1[s] = 1.0f - a1[s];
    }

    float dcur[NSLOT]  = {0.f, 0.f, 0.f, 0.f};
    float mem1[NSLOT]  = {0.f, 0.f, 0.f, 0.f};
    float sprev[NSLOT] = {0.f, 0.f, 0.f, 0.f};
    unsigned long long sm0 = 0, sm1 = 0, sm2 = 0, sm3 = 0;

    // Readout state (lanes 0..2 own one output each)
    float a2 = 0.f, oma2 = 0.f, b2v = 0.f, mem2 = 0.f, acc = 0.f;
    if (lane < N_OUT) {
        a2   = sigmoidf_(tau_m2[lane]);
        oma2 = 1.0f - a2;
        b2v  = b2[lane];
    }

    const float4* xr4 = reinterpret_cast<const float4*>(x + (size_t)b * T_STEPS * N_IN);

    // Prologue: chunk 0 -> LDS buffer 0; chunk 1 -> gx registers.
    {
        float4* d4 = reinterpret_cast<float4*>(&xs[0][0]);
#pragma unroll
        for (int k = 0; k < GXK; ++k) d4[lane + WAVE * k] = xr4[lane + WAVE * k];
    }
    float4 gx[GXK];
#pragma unroll
    for (int k = 0; k < GXK; ++k) gx[k] = xr4[XS_F4 + lane + WAVE * k];

    float xa[N_IN], xb[N_IN];
    LOADX(xa, 0, 0);

    int tbase = 0;
    for (int c = 0; c < NCHUNK; ++c) {
        const int buf = c & 1;
#pragma unroll 1
        for (int s = 0; s < CHUNK - 2; s += 2) {
            STEP_CORE(xa)
            LOADX(xb, buf, s + 1)      // prefetch; latency hides under next FMAs
            READOUT(tbase + s)
            STEP_CORE(xb)
            LOADX(xa, buf, s + 2)
            READOUT(tbase + s + 1)
        }
        // step CHUNK-2 (xa), prefetch last row of this chunk
        STEP_CORE(xa)
        LOADX(xb, buf, CHUNK - 1)
        READOUT(tbase + CHUNK - 2)
        // step CHUNK-1 (xb) + chunk swap: write staged regs -> other buffer,
        // issue global loads for chunk c+2, then prefetch xa from new buffer.
        STEP_CORE(xb)
        if (c + 1 < NCHUNK) {
            float4* d4 = reinterpret_cast<float4*>(&xs[buf ^ 1][0]);
#pragma unroll
            for (int k = 0; k < GXK; ++k) d4[lane + WAVE * k] = gx[k];
        }
        if (c + 2 < NCHUNK) {
#pragma unroll
            for (int k = 0; k < GXK; ++k)
                gx[k] = xr4[(size_t)(c + 2) * XS_F4 + lane + WAVE * k];
        }
        READOUT(tbase + CHUNK - 1)
        if (c + 1 < NCHUNK) LOADX(xa, buf ^ 1, 0)
        tbase += CHUNK;
    }

    if (lane < N_OUT) out[(size_t)b * N_OUT + lane] = acc / (float)T_STEPS;
}

extern "C" void kernel_launch(void* const* d_in, const int* in_sizes, int n_in,
                              void* d_out, int out_size, void* d_ws, size_t ws_size,
                              hipStream_t stream) {
    const float* x      = (const float*)d_in[0];
    const float* W1     = (const float*)d_in[1];
    const float* b1     = (const float*)d_in[2];
    const float* tau_n  = (const float*)d_in[3];
    const float* tau_m1 = (const float*)d_in[4];
    const float* W2     = (const float*)d_in[5];
    const float* b2     = (const float*)d_in[6];
    const float* tau_m2 = (const float*)d_in[7];
    const float* mask   = (const float*)d_in[8];
    float* out = (float*)d_out;

    const int B = in_sizes[0] / (T_STEPS * N_IN);  // 512

    hipLaunchKernelGGL(dhsnn_wave_kernel, dim3(B), dim3(WAVE), 0, stream,
                       x, W1, b1, tau_n, tau_m1, W2, b2, tau_m2, mask, out);
}

// Round 4
// 850.063 us; speedup vs baseline: 2.2287x; 1.0169x over previous
//
#include <hip/hip_runtime.h>
#include <cstdint>
#include <cstddef>

#define N_IN    32
#define N_HID   200
#define N_OUT   3
#define FAN_IN  232   // N_IN + N_HID
#define T_STEPS 2000
#define WAVE    64

#define CHUNK   40                    // timesteps per LDS buffer
#define NCHUNK  (T_STEPS / CHUNK)     // 50, exact
#define XS_F4   (CHUNK * N_IN / 4)    // 320 float4 per buffer
#define GXK     (XS_F4 / WAVE)        // 5 float4 per lane per chunk

typedef float f2 __attribute__((ext_vector_type(2)));

__device__ __forceinline__ float sigmoidf_(float v) { return 1.0f / (1.0f + expf(-v)); }
__device__ __forceinline__ f2 mkf2(float a, float b) { f2 r; r.x = a; r.y = b; return r; }

// ---- packed f32 primitives (VOP3P, guaranteed via inline asm) ----
// acc.lo += w.lo * x.lo ; acc.hi += w.hi * x.lo   (broadcast x low half)
__device__ __forceinline__ void pkfma_lo(f2& acc, f2 w, f2 x) {
    asm("v_pk_fma_f32 %0, %1, %2, %0 op_sel:[0,0,0] op_sel_hi:[1,0,1]"
        : "+v"(acc) : "v"(w), "v"(x));
}
// acc.lo += w.lo * x.hi ; acc.hi += w.hi * x.hi   (broadcast x high half)
__device__ __forceinline__ void pkfma_hi(f2& acc, f2 w, f2 x) {
    asm("v_pk_fma_f32 %0, %1, %2, %0 op_sel:[0,1,0] op_sel_hi:[1,1,1]"
        : "+v"(acc) : "v"(w), "v"(x));
}
__device__ __forceinline__ f2 pkfma(f2 a, f2 b, f2 c) {
    f2 d; asm("v_pk_fma_f32 %0, %1, %2, %3" : "=v"(d) : "v"(a), "v"(b), "v"(c)); return d;
}
__device__ __forceinline__ f2 pkmul(f2 a, f2 b) {
    f2 d; asm("v_pk_mul_f32 %0, %1, %2" : "=v"(d) : "v"(a), "v"(b)); return d;
}
__device__ __forceinline__ f2 pkadd(f2 a, f2 b) {
    f2 d; asm("v_pk_add_f32 %0, %1, %2" : "=v"(d) : "v"(a), "v"(b)); return d;
}

// Broadcast-read one timestep's 32 x values from LDS into 16 packed f2.
#define LOADX(DST, BUF, S)                                                        \
    {                                                                             \
        const float4* xp4_ = reinterpret_cast<const float4*>(&xs[BUF][(S) * N_IN]); \
        _Pragma("unroll")                                                         \
        for (int q_ = 0; q_ < 8; ++q_) {                                          \
            float4 v_ = xp4_[q_];                                                 \
            DST[2 * q_]     = mkf2(v_.x, v_.y);                                   \
            DST[2 * q_ + 1] = mkf2(v_.z, v_.w);                                   \
        }                                                                         \
    }

// Rare-path recurrent contribution of spiking neuron J (global index)
#define RECADD(J)                                                                 \
    { int o_ = N_IN + (J);                                                        \
      cur01.x += W1[(size_t)h0 * FAN_IN + o_] * mask[(size_t)h0 * FAN_IN + o_];   \
      cur01.y += W1[(size_t)h1 * FAN_IN + o_] * mask[(size_t)h1 * FAN_IN + o_];   \
      cur23.x += W1[(size_t)h2 * FAN_IN + o_] * mask[(size_t)h2 * FAN_IN + o_];   \
      cur23.y += W1[(size_t)h3 * FAN_IN + o_] * mask[(size_t)h3 * FAN_IN + o_]; }

#define STEP_CORE(XV)                                                             \
    {                                                                             \
        f2 a01_[4], a23_[4];                                                      \
        a01_[0] = bias01; a01_[1] = zz; a01_[2] = zz; a01_[3] = zz;               \
        a23_[0] = bias23; a23_[1] = zz; a23_[2] = zz; a23_[3] = zz;               \
        _Pragma("unroll")                                                         \
        for (int q_ = 0; q_ < 16; ++q_) {                                         \
            pkfma_lo(a01_[q_ & 3], w01[2 * q_],     XV[q_]);                      \
            pkfma_hi(a01_[q_ & 3], w01[2 * q_ + 1], XV[q_]);                      \
            pkfma_lo(a23_[q_ & 3], w23[2 * q_],     XV[q_]);                      \
            pkfma_hi(a23_[q_ & 3], w23[2 * q_ + 1], XV[q_]);                      \
        }                                                                         \
        f2 cur01 = pkadd(pkadd(a01_[0], a01_[1]), pkadd(a01_[2], a01_[3]));       \
        f2 cur23 = pkadd(pkadd(a23_[0], a23_[1]), pkadd(a23_[2], a23_[3]));       \
        if (__builtin_expect((int)aprev, 0)) {                                    \
            unsigned long long m_;                                                \
            m_ = sm0; while (m_) { int j_ = __builtin_ctzll(m_);       m_ &= m_ - 1; RECADD(j_) } \
            m_ = sm1; while (m_) { int j_ = 64  + __builtin_ctzll(m_); m_ &= m_ - 1; RECADD(j_) } \
            m_ = sm2; while (m_) { int j_ = 128 + __builtin_ctzll(m_); m_ &= m_ - 1; RECADD(j_) } \
            m_ = sm3; while (m_) { int j_ = 192 + __builtin_ctzll(m_); m_ &= m_ - 1; RECADD(j_) } \
        }                                                                         \
        dcur01 = pkfma(beta01, dcur01, pkmul(omb01, cur01));                      \
        dcur23 = pkfma(beta23, dcur23, pkmul(omb23, cur23));                      \
        mem01 = pkfma(a1_01, mem01, pkfma(oma1_01, dcur01, nsp01));               \
        mem23 = pkfma(a1_23, mem23, pkfma(oma1_23, dcur23, nsp23));               \
        float mx_ = fmaxf(fmaxf(mem01.x, mem01.y), fmaxf(mem23.x, mem23.y));      \
        bool an_ = __any(mx_ > 1.0f);                                             \
        if (__builtin_expect((int)an_, 0)) {                                      \
            sm0 = __ballot(mem01.x > 1.0f);                                       \
            sm1 = __ballot(mem01.y > 1.0f);                                       \
            sm2 = __ballot(mem23.x > 1.0f);                                       \
            sm3 = __ballot(mem23.y > 1.0f) & 0xFFull;  /* neurons 192..199 */     \
            nsp01.x = (mem01.x > 1.0f) ? -1.0f : 0.0f;                            \
            nsp01.y = (mem01.y > 1.0f) ? -1.0f : 0.0f;                            \
            nsp23.x = (mem23.x > 1.0f) ? -1.0f : 0.0f;                            \
            nsp23.y = (mem23.y > 1.0f) ? -1.0f : 0.0f;                            \
        } else {                                                                  \
            nsp01 = zz; nsp23 = zz;                                               \
        }                                                                         \
        aprev = an_;                                                              \
    }

// Leaky readout using THIS step's spikes. All lanes compute (lanes>=3 dup
// output 0 harmlessly); acc gated by SALU-selected 0/1 multiplier.
#define READOUT(TCUR)                                                            \
    {                                                                            \
        if (__builtin_expect((int)aprev, 0)) {                                   \
            float r_ = b2v;                                                      \
            unsigned long long m_;                                               \
            m_ = sm0; while (m_) { int j_ = __builtin_ctzll(m_);       m_ &= m_ - 1; r_ += W2L[ro + j_]; } \
            m_ = sm1; while (m_) { int j_ = 64  + __builtin_ctzll(m_); m_ &= m_ - 1; r_ += W2L[ro + j_]; } \
            m_ = sm2; while (m_) { int j_ = 128 + __builtin_ctzll(m_); m_ &= m_ - 1; r_ += W2L[ro + j_]; } \
            m_ = sm3; while (m_) { int j_ = 192 + __builtin_ctzll(m_); m_ &= m_ - 1; r_ += W2L[ro + j_]; } \
            mem2 = fmaf(a2, mem2, oma2 * r_);                                    \
        } else {                                                                 \
            mem2 = fmaf(a2, mem2, obr);                                          \
        }                                                                        \
        float gf_ = ((TCUR) > 0) ? 1.0f : 0.0f;                                  \
        acc = fmaf(gf_, mem2, acc);                                              \
    }

__global__ __launch_bounds__(WAVE, 1) void dhsnn_pk_kernel(
    const float* __restrict__ x,       // [B, T, N_IN]
    const float* __restrict__ W1,      // [N_HID, FAN_IN]
    const float* __restrict__ b1,      // [N_HID]
    const float* __restrict__ tau_n,   // [N_HID, 1]
    const float* __restrict__ tau_m1,  // [N_HID]
    const float* __restrict__ W2,      // [N_OUT, N_HID]
    const float* __restrict__ b2,      // [N_OUT]
    const float* __restrict__ tau_m2,  // [N_OUT]
    const float* __restrict__ mask,    // [N_HID, FAN_IN]
    float* __restrict__ out)           // [B, N_OUT]
{
    const int b    = blockIdx.x;
    const int lane = threadIdx.x;      // single wave per block

    __shared__ float W2L[N_OUT * N_HID];        // 2.4 KB
    __shared__ float xs[2][CHUNK * N_IN];       // 10 KB

    for (int i = lane; i < N_OUT * N_HID; i += WAVE) W2L[i] = W2[i];

    const f2 zz = mkf2(0.f, 0.f);

    // Slot->neuron mapping: slot s = neuron s*64+lane (slot3 lanes>=8 dup 199)
    const int h0 = lane;
    const int h1 = 64 + lane;
    const int h2 = 128 + lane;
    const int h3 = (192 + lane < N_HID) ? 192 + lane : N_HID - 1;

    // Packed input weights: w01[j] = {wx[h0][j], wx[h1][j]}
    f2 w01[N_IN], w23[N_IN];
#pragma unroll
    for (int j = 0; j < N_IN; ++j) {
        w01[j] = mkf2(W1[(size_t)h0 * FAN_IN + j] * mask[(size_t)h0 * FAN_IN + j],
                      W1[(size_t)h1 * FAN_IN + j] * mask[(size_t)h1 * FAN_IN + j]);
        w23[j] = mkf2(W1[(size_t)h2 * FAN_IN + j] * mask[(size_t)h2 * FAN_IN + j],
                      W1[(size_t)h3 * FAN_IN + j] * mask[(size_t)h3 * FAN_IN + j]);
    }
    const f2 bias01 = mkf2(b1[h0], b1[h1]);
    const f2 bias23 = mkf2(b1[h2], b1[h3]);
    const f2 beta01 = mkf2(sigmoidf_(tau_n[h0]), sigmoidf_(tau_n[h1]));
    const f2 beta23 = mkf2(sigmoidf_(tau_n[h2]), sigmoidf_(tau_n[h3]));
    const f2 a1_01  = mkf2(sigmoidf_(tau_m1[h0]), sigmoidf_(tau_m1[h1]));
    const f2 a1_23  = mkf2(sigmoidf_(tau_m1[h2]), sigmoidf_(tau_m1[h3]));
    const f2 omb01  = mkf2(1.f - beta01.x, 1.f - beta01.y);
    const f2 omb23  = mkf2(1.f - beta23.x, 1.f - beta23.y);
    const f2 oma1_01 = mkf2(1.f - a1_01.x, 1.f - a1_01.y);
    const f2 oma1_23 = mkf2(1.f - a1_23.x, 1.f - a1_23.y);

    // Recurrent state (packed across slot pairs)
    f2 dcur01 = zz, dcur23 = zz, mem01 = zz, mem23 = zz, nsp01 = zz, nsp23 = zz;
    unsigned long long sm0 = 0, sm1 = 0, sm2 = 0, sm3 = 0;
    bool aprev = false;

    // Readout state (lane i<3 owns output i; others dup output 0)
    const int lo_ = (lane < N_OUT) ? lane : 0;
    const int ro  = lo_ * N_HID;
    const float a2   = sigmoidf_(tau_m2[lo_]);
    const float oma2 = 1.0f - a2;
    const float b2v  = b2[lo_];
    const float obr  = oma2 * b2v;
    float mem2 = 0.f, acc = 0.f;

    const float4* xr4 = reinterpret_cast<const float4*>(x + (size_t)b * T_STEPS * N_IN);

    // Prologue: chunk 0 -> LDS buffer 0; chunk 1 -> gx registers.
    {
        float4* d4 = reinterpret_cast<float4*>(&xs[0][0]);
#pragma unroll
        for (int k = 0; k < GXK; ++k) d4[lane + WAVE * k] = xr4[lane + WAVE * k];
    }
    float4 gx[GXK];
#pragma unroll
    for (int k = 0; k < GXK; ++k) gx[k] = xr4[XS_F4 + lane + WAVE * k];

    f2 xa[16], xb[16], xc[16], xd[16];
    LOADX(xa, 0, 0)
    LOADX(xb, 0, 1)

    int tb = 0;
#pragma unroll 1
    for (int c = 0; c < NCHUNK; ++c) {
        const int buf = c & 1;
#pragma unroll 1
        for (int sg = 0; sg < CHUNK - 4; sg += 4) {     // sg = 0,4,...,32
            STEP_CORE(xa) LOADX(xc, buf, sg + 2) READOUT(tb + sg)
            STEP_CORE(xb) LOADX(xd, buf, sg + 3) READOUT(tb + sg + 1)
            STEP_CORE(xc) LOADX(xa, buf, sg + 4) READOUT(tb + sg + 2)
            STEP_CORE(xd) LOADX(xb, buf, sg + 5) READOUT(tb + sg + 3)
        }
        // steps 36..39 of the chunk
        STEP_CORE(xa) LOADX(xc, buf, CHUNK - 2) READOUT(tb + CHUNK - 4)
        STEP_CORE(xb) LOADX(xd, buf, CHUNK - 1) READOUT(tb + CHUNK - 3)
        STEP_CORE(xc) READOUT(tb + CHUNK - 2)
        STEP_CORE(xd)
        if (c + 1 < NCHUNK) {   // stage next chunk from regs -> LDS
            float4* d4 = reinterpret_cast<float4*>(&xs[buf ^ 1][0]);
#pragma unroll
            for (int k = 0; k < GXK; ++k) d4[lane + WAVE * k] = gx[k];
        }
        if (c + 2 < NCHUNK) {   // issue global loads 2 chunks ahead
#pragma unroll
            for (int k = 0; k < GXK; ++k)
                gx[k] = xr4[(size_t)(c + 2) * XS_F4 + lane + WAVE * k];
        }
        READOUT(tb + CHUNK - 1)
        if (c + 1 < NCHUNK) { LOADX(xa, buf ^ 1, 0) LOADX(xb, buf ^ 1, 1) }
        tb += CHUNK;
    }

    if (lane < N_OUT) out[(size_t)b * N_OUT + lane] = acc / (float)T_STEPS;
}

extern "C" void kernel_launch(void* const* d_in, const int* in_sizes, int n_in,
                              void* d_out, int out_size, void* d_ws, size_t ws_size,
                              hipStream_t stream) {
    const float* x      = (const float*)d_in[0];
    const float* W1     = (const float*)d_in[1];
    const float* b1     = (const float*)d_in[2];
    const float* tau_n  = (const float*)d_in[3];
    const float* tau_m1 = (const float*)d_in[4];
    const float* W2     = (const float*)d_in[5];
    const float* b2     = (const float*)d_in[6];
    const float* tau_m2 = (const float*)d_in[7];
    const float* mask   = (const float*)d_in[8];
    float* out = (float*)d_out;

    const int B = in_sizes[0] / (T_STEPS * N_IN);  // 512

    hipLaunchKernelGGL(dhsnn_pk_kernel, dim3(B), dim3(WAVE), 0, stream,
                       x, W1, b1, tau_n, tau_m1, W2, b2, tau_m2, mask, out);
}

// Round 5
// 738.759 us; speedup vs baseline: 2.5645x; 1.1507x over previous
//
#include <hip/hip_runtime.h>
#include <cstdint>
#include <cstddef>

#define N_IN    32
#define N_HID   200
#define N_OUT   3
#define FAN_IN  232   // N_IN + N_HID
#define T_STEPS 2000
#define CHUNK   40                    // timesteps per LDS buffer
#define NCHUNK  (T_STEPS / CHUNK)     // 50, exact
#define XS_FLOATS (CHUNK * N_IN)      // 1280 floats per buffer
#define XS_F4   (XS_FLOATS / 4)       // 320 float4 per buffer
#define THRD    0.98f                 // dirty margin below VTH=1.0

__device__ __forceinline__ float sigmoidf_(float v) { return 1.0f / (1.0f + expf(-v)); }

// ============================ K1: verify-scan ============================
// One thread per (b,h) stream; zero-spike mem1 trajectory; flag if it ever
// approaches VTH. 512 blocks x 256 threads -> 8 waves/CU.

#define LOADX1(DST, BUF, S)                                                       \
    {                                                                             \
        const float4* p_ = reinterpret_cast<const float4*>(&xs[BUF][(S) * N_IN]); \
        _Pragma("unroll")                                                         \
        for (int q_ = 0; q_ < 8; ++q_) {                                          \
            float4 v_ = p_[q_];                                                   \
            DST[4*q_+0] = v_.x; DST[4*q_+1] = v_.y;                               \
            DST[4*q_+2] = v_.z; DST[4*q_+3] = v_.w;                               \
        }                                                                         \
    }

#define STEP1(XV)                                                                 \
    {                                                                             \
        float c0 = bias, c1 = 0.f, c2 = 0.f, c3 = 0.f;                            \
        _Pragma("unroll")                                                         \
        for (int j_ = 0; j_ < N_IN; j_ += 4) {                                    \
            c0 = fmaf(XV[j_ + 0], w[j_ + 0], c0);                                 \
            c1 = fmaf(XV[j_ + 1], w[j_ + 1], c1);                                 \
            c2 = fmaf(XV[j_ + 2], w[j_ + 2], c2);                                 \
            c3 = fmaf(XV[j_ + 3], w[j_ + 3], c3);                                 \
        }                                                                         \
        float cur_ = (c0 + c1) + (c2 + c3);                                       \
        dcur = fmaf(beta, dcur, omb * cur_);                                      \
        mem1 = fmaf(a1, mem1, oma1 * dcur);                                       \
        pk = fmaxf(pk, mem1);                                                     \
    }

__global__ __launch_bounds__(256, 2) void k1_scan(
    const float* __restrict__ x, const float* __restrict__ W1,
    const float* __restrict__ b1, const float* __restrict__ tau_n,
    const float* __restrict__ tau_m1, const float* __restrict__ mask,
    int* __restrict__ dirty)
{
    const int b = blockIdx.x, tid = threadIdx.x;
    __shared__ float xs[2][XS_FLOATS];   // 10.25 KB

    if (tid == 0) dirty[b] = 0;

    const int h = (tid < N_HID) ? tid : (N_HID - 1);
    float w[N_IN];
#pragma unroll
    for (int j = 0; j < N_IN; ++j)
        w[j] = W1[(size_t)h * FAN_IN + j] * mask[(size_t)h * FAN_IN + j];
    const float bias = b1[h];
    const float beta = sigmoidf_(tau_n[h]);
    const float a1   = sigmoidf_(tau_m1[h]);
    const float omb  = 1.f - beta;
    const float oma1 = 1.f - a1;

    float dcur = 0.f, mem1 = 0.f, pk = -1.f;

    const float* xrow = x + (size_t)b * T_STEPS * N_IN;

    // Stage chunk 0 -> LDS, chunk 1 -> regs
#pragma unroll
    for (int k = 0; k < 5; ++k) xs[0][tid + 256 * k] = xrow[tid + 256 * k];
    float gx[5];
#pragma unroll
    for (int k = 0; k < 5; ++k) gx[k] = xrow[XS_FLOATS + tid + 256 * k];
    __syncthreads();

    float xa[N_IN], xb[N_IN], xc[N_IN], xd[N_IN];
    LOADX1(xa, 0, 0) LOADX1(xb, 0, 1)

#pragma unroll 1
    for (int c = 0; c < NCHUNK; ++c) {
        const int buf = c & 1;
#pragma unroll 1
        for (int sg = 0; sg < CHUNK - 4; sg += 4) {   // sg = 0..32
            STEP1(xa) LOADX1(xc, buf, sg + 2)
            STEP1(xb) LOADX1(xd, buf, sg + 3)
            STEP1(xc) LOADX1(xa, buf, sg + 4)
            STEP1(xd) LOADX1(xb, buf, sg + 5)
        }
        STEP1(xa) LOADX1(xc, buf, CHUNK - 2)
        STEP1(xb) LOADX1(xd, buf, CHUNK - 1)
        STEP1(xc)
        STEP1(xd)
        __syncthreads();   // all waves done with chunk c (and long done with buf^1)
        if (c + 1 < NCHUNK) {
#pragma unroll
            for (int k = 0; k < 5; ++k) xs[buf ^ 1][tid + 256 * k] = gx[k];
        }
        if (c + 2 < NCHUNK) {
#pragma unroll
            for (int k = 0; k < 5; ++k)
                gx[k] = xrow[(size_t)(c + 2) * XS_FLOATS + tid + 256 * k];
        }
        __syncthreads();   // staged writes visible
        if (c + 1 < NCHUNK) { LOADX1(xa, buf ^ 1, 0) LOADX1(xb, buf ^ 1, 1) }
    }

    if (pk > THRD) atomicOr(&dirty[b], 1);
}

// ============================ K3: emit ============================
// Clean batch: spikes provably zero -> mem2 recursion depends only on b2.
// Dirty batch: exact single-wave resimulation (round-2 validated structure).

#define NSLOT 4

#define LOADXE(DST, BUF, S)                                                       \
    {                                                                             \
        const float4* xp4_ = reinterpret_cast<const float4*>(&xs[BUF][(S) * N_IN]); \
        _Pragma("unroll")                                                         \
        for (int q_ = 0; q_ < 8; ++q_) {                                          \
            float4 v_ = xp4_[q_];                                                 \
            DST[4*q_+0] = v_.x; DST[4*q_+1] = v_.y;                               \
            DST[4*q_+2] = v_.z; DST[4*q_+3] = v_.w;                               \
        }                                                                         \
    }

#define STEPE(XV)                                                                 \
    {                                                                             \
        float cur[NSLOT];                                                         \
        _Pragma("unroll")                                                         \
        for (int s_ = 0; s_ < NSLOT; ++s_) {                                      \
            float c0 = biasE[s_], c1 = 0.f, c2 = 0.f, c3 = 0.f;                   \
            _Pragma("unroll")                                                     \
            for (int j_ = 0; j_ < N_IN; j_ += 4) {                                \
                c0 = fmaf(XV[j_ + 0], wxE[s_][j_ + 0], c0);                       \
                c1 = fmaf(XV[j_ + 1], wxE[s_][j_ + 1], c1);                       \
                c2 = fmaf(XV[j_ + 2], wxE[s_][j_ + 2], c2);                       \
                c3 = fmaf(XV[j_ + 3], wxE[s_][j_ + 3], c3);                       \
            }                                                                     \
            cur[s_] = (c0 + c1) + (c2 + c3);                                      \
        }                                                                         \
        if (sm0 | sm1 | sm2 | sm3) {                                              \
            unsigned long long mm_[NSLOT] = {sm0, sm1, sm2, sm3};                 \
            _Pragma("unroll")                                                     \
            for (int ss_ = 0; ss_ < NSLOT; ++ss_) {                               \
                unsigned long long m_ = mm_[ss_];                                 \
                while (m_) {                                                      \
                    int j_ = (ss_ << 6) + __builtin_ctzll(m_);                    \
                    m_ &= m_ - 1;                                                 \
                    _Pragma("unroll")                                             \
                    for (int s_ = 0; s_ < NSLOT; ++s_) {                          \
                        size_t o_ = (size_t)hcE[s_] * FAN_IN + N_IN + j_;         \
                        cur[s_] += W1[o_] * mask[o_];                             \
                    }                                                             \
                }                                                                 \
            }                                                                     \
        }                                                                         \
        _Pragma("unroll")                                                         \
        for (int s_ = 0; s_ < NSLOT; ++s_) {                                      \
            dcurE[s_] = fmaf(betaE[s_], dcurE[s_], ombE[s_] * cur[s_]);           \
            mem1E[s_] = fmaf(a1E[s_], mem1E[s_], fmaf(oma1E[s_], dcurE[s_], -sprevE[s_])); \
            sprevE[s_] = (mem1E[s_] > 1.0f) ? 1.0f : 0.0f;                        \
        }                                                                         \
        sm0 = __ballot(mem1E[0] > 1.0f);                                          \
        sm1 = __ballot(mem1E[1] > 1.0f);                                          \
        sm2 = __ballot(mem1E[2] > 1.0f);                                          \
        sm3 = __ballot(mem1E[3] > 1.0f) & 0xFFull;                                \
    }

#define READE(TCUR)                                                               \
    {                                                                             \
        if (lane < N_OUT) {                                                       \
            float r_ = b2v;                                                       \
            unsigned long long mm_[NSLOT] = {sm0, sm1, sm2, sm3};                 \
            _Pragma("unroll")                                                     \
            for (int ss_ = 0; ss_ < NSLOT; ++ss_) {                               \
                unsigned long long m_ = mm_[ss_];                                 \
                while (m_) {                                                      \
                    int j_ = (ss_ << 6) + __builtin_ctzll(m_);                    \
                    m_ &= m_ - 1;                                                 \
                    r_ += W2L[lane * N_HID + j_];                                 \
                }                                                                 \
            }                                                                     \
            mem2 = fmaf(a2, mem2, oma2 * r_);                                     \
            if ((TCUR) > 0) acc += mem2;                                          \
        }                                                                         \
    }

__global__ __launch_bounds__(64, 1) void k3_emit(
    const float* __restrict__ x, const float* __restrict__ W1,
    const float* __restrict__ b1, const float* __restrict__ tau_n,
    const float* __restrict__ tau_m1, const float* __restrict__ W2,
    const float* __restrict__ b2, const float* __restrict__ tau_m2,
    const float* __restrict__ mask, const int* __restrict__ dirty,
    float* __restrict__ out)
{
    const int b = blockIdx.x, lane = threadIdx.x;
    __shared__ float W2L[N_OUT * N_HID];
    __shared__ float xs[2][XS_FLOATS];

    if (dirty[b] == 0) {
        // Provably spike-free: mem2(t) = a2*mem2 + (1-a2)*b2, exact.
        if (lane < N_OUT) {
            const float a2   = sigmoidf_(tau_m2[lane]);
            const float oma2 = 1.f - a2;
            const float obr  = oma2 * b2[lane];
            float mem2 = obr, acc = 0.f;   // after step t=0
#pragma unroll 8
            for (int t = 1; t < T_STEPS; ++t) { mem2 = fmaf(a2, mem2, obr); acc += mem2; }
            out[(size_t)b * N_OUT + lane] = acc / (float)T_STEPS;
        }
        return;
    }

    // ---------- exact resimulation (cold path) ----------
    for (int i = lane; i < N_OUT * N_HID; i += 64) W2L[i] = W2[i];

    int hcE[NSLOT];
    float wxE[NSLOT][N_IN];
    float biasE[NSLOT], betaE[NSLOT], a1E[NSLOT], ombE[NSLOT], oma1E[NSLOT];
#pragma unroll
    for (int s = 0; s < NSLOT; ++s) {
        int hh = s * 64 + lane;
        hcE[s] = (hh < N_HID) ? hh : (N_HID - 1);
        const float* wr = W1  + (size_t)hcE[s] * FAN_IN;
        const float* mr = mask + (size_t)hcE[s] * FAN_IN;
#pragma unroll
        for (int j = 0; j < N_IN; ++j) wxE[s][j] = wr[j] * mr[j];
        biasE[s] = b1[hcE[s]];
        betaE[s] = sigmoidf_(tau_n[hcE[s]]);
        a1E[s]   = sigmoidf_(tau_m1[hcE[s]]);
        ombE[s]  = 1.f - betaE[s];
        oma1E[s] = 1.f - a1E[s];
    }

    float dcurE[NSLOT]  = {0.f, 0.f, 0.f, 0.f};
    float mem1E[NSLOT]  = {0.f, 0.f, 0.f, 0.f};
    float sprevE[NSLOT] = {0.f, 0.f, 0.f, 0.f};
    unsigned long long sm0 = 0, sm1 = 0, sm2 = 0, sm3 = 0;

    const int lo_ = (lane < N_OUT) ? lane : 0;
    const float a2   = sigmoidf_(tau_m2[lo_]);
    const float oma2 = 1.f - a2;
    const float b2v  = b2[lo_];
    float mem2 = 0.f, acc = 0.f;

    const float4* xr4 = reinterpret_cast<const float4*>(x + (size_t)b * T_STEPS * N_IN);

    {
        float4* d4 = reinterpret_cast<float4*>(&xs[0][0]);
#pragma unroll
        for (int k = 0; k < 5; ++k) d4[lane + 64 * k] = xr4[lane + 64 * k];
    }
    float4 gx[5];
#pragma unroll
    for (int k = 0; k < 5; ++k) gx[k] = xr4[XS_F4 + lane + 64 * k];

    float xa[N_IN], xb[N_IN];
    LOADXE(xa, 0, 0)

    int tb = 0;
#pragma unroll 1
    for (int c = 0; c < NCHUNK; ++c) {
        const int buf = c & 1;
#pragma unroll 1
        for (int s = 0; s < CHUNK - 2; s += 2) {
            STEPE(xa) LOADXE(xb, buf, s + 1) READE(tb + s)
            STEPE(xb) LOADXE(xa, buf, s + 2) READE(tb + s + 1)
        }
        STEPE(xa) LOADXE(xb, buf, CHUNK - 1) READE(tb + CHUNK - 2)
        STEPE(xb)
        if (c + 1 < NCHUNK) {
            float4* d4 = reinterpret_cast<float4*>(&xs[buf ^ 1][0]);
#pragma unroll
            for (int k = 0; k < 5; ++k) d4[lane + 64 * k] = gx[k];
        }
        if (c + 2 < NCHUNK) {
#pragma unroll
            for (int k = 0; k < 5; ++k)
                gx[k] = xr4[(size_t)(c + 2) * XS_F4 + lane + 64 * k];
        }
        READE(tb + CHUNK - 1)
        if (c + 1 < NCHUNK) LOADXE(xa, buf ^ 1, 0)
        tb += CHUNK;
    }

    if (lane < N_OUT) out[(size_t)b * N_OUT + lane] = acc / (float)T_STEPS;
}

extern "C" void kernel_launch(void* const* d_in, const int* in_sizes, int n_in,
                              void* d_out, int out_size, void* d_ws, size_t ws_size,
                              hipStream_t stream) {
    const float* x      = (const float*)d_in[0];
    const float* W1     = (const float*)d_in[1];
    const float* b1     = (const float*)d_in[2];
    const float* tau_n  = (const float*)d_in[3];
    const float* tau_m1 = (const float*)d_in[4];
    const float* W2     = (const float*)d_in[5];
    const float* b2     = (const float*)d_in[6];
    const float* tau_m2 = (const float*)d_in[7];
    const float* mask   = (const float*)d_in[8];
    float* out = (float*)d_out;
    int*   dirty = (int*)d_ws;

    const int B = in_sizes[0] / (T_STEPS * N_IN);  // 512

    hipLaunchKernelGGL(k1_scan, dim3(B), dim3(256), 0, stream,
                       x, W1, b1, tau_n, tau_m1, mask, dirty);
    hipLaunchKernelGGL(k3_emit, dim3(B), dim3(64), 0, stream,
                       x, W1, b1, tau_n, tau_m1, W2, b2, tau_m2, mask, dirty, out);
}

// Round 6
// 273.986 us; speedup vs baseline: 6.9146x; 2.6963x over previous
//
#include <hip/hip_runtime.h>
#include <cstdint>
#include <cstddef>

#define N_IN    32
#define N_HID   200
#define N_OUT   3
#define FAN_IN  232   // N_IN + N_HID
#define T_STEPS 2000
#define CHUNK   40                    // timesteps per chunk
#define NCHUNK  (T_STEPS / CHUNK)     // 50, exact
#define TPAD    48                    // padded timesteps (3 t-tiles of 16)
#define XROW    40                    // bf16 element stride of xbf rows (bank spread)
#define CURST   212                   // float stride of curL rows [t][h] (16B-aligned, bank-spread)
#define XS_FLOATS (CHUNK * N_IN)      // 1280
#define XS_F4     (XS_FLOATS / 4)     // 320 float4 per chunk
#define THRD    0.90f                 // dirty threshold (VTH=1.0; mem1 max ~0.4; bf16 err ~1e-3)

typedef float  f32x4 __attribute__((ext_vector_type(4)));
typedef short  s16x8 __attribute__((ext_vector_type(8)));
typedef unsigned short u16;
typedef unsigned long long u64;

__device__ __forceinline__ float sigmoidf_(float v) { return 1.0f / (1.0f + expf(-v)); }

__device__ __forceinline__ u16 f2bf(float f) {     // fp32 -> bf16 RNE
    union { float f; unsigned u; } v; v.f = f;
    unsigned r = v.u + 0x7FFFu + ((v.u >> 16) & 1u);
    return (u16)(r >> 16);
}
__device__ __forceinline__ float bf2f(u16 h) {
    union { float f; unsigned u; } v; v.u = ((unsigned)h) << 16; return v.f;
}

// ============================ K1: MFMA verify-scan ============================
// Per block b: chunked GEMM cur^T[h][t] = (W*mask)[h][:32] @ X^T on matrix cores,
// then a cheap 2-FMA/step zero-spike recurrence scan per neuron. Flags dirty[b]
// if any mem1 approaches VTH. Self-verifies MFMA layout once -> bad[b] fallback.

__global__ __launch_bounds__(256, 2) void k1_scan(
    const float* __restrict__ x, const float* __restrict__ W1,
    const float* __restrict__ b1, const float* __restrict__ tau_n,
    const float* __restrict__ tau_m1, const float* __restrict__ mask,
    int* __restrict__ dirty, int* __restrict__ bad)
{
    const int b    = blockIdx.x;
    const int tid  = threadIdx.x;
    const int wid  = tid >> 6;
    const int lane = tid & 63;

    __shared__ u16   xbf[2][TPAD * XROW];   // 2 x 3840 B = 7.7 KB (bf16 X chunks)
    __shared__ float curL[TPAD * CURST];    // 40.7 KB, [t][h] layout

    if (tid == 0) { dirty[b] = 0; bad[b] = 0; }

    // ---- A fragments (static): wave w owns h-tiles {w, w+4, w+8, (12 if w==0)} ----
    const int ntile = (wid == 0) ? 4 : 3;
    s16x8 af[4];
#pragma unroll
    for (int i = 0; i < 4; ++i) {
        const int tile = wid + 4 * i;
        const int h    = tile * 16 + (lane & 15);
        const int k0   = (lane >> 4) * 8;
#pragma unroll
        for (int j = 0; j < 8; ++j) {
            float wv = 0.f;
            if (i < ntile && h < N_HID) {
                size_t o = (size_t)h * FAN_IN + k0 + j;
                wv = W1[o] * mask[o];
            }
            af[i][j] = (short)f2bf(wv);
        }
    }

    // ---- scan parameters (thread = neuron) ----
    const int hidx = (tid < N_HID) ? tid : (N_HID - 1);
    const float beta = sigmoidf_(tau_n[hidx]);
    const float a1   = sigmoidf_(tau_m1[hidx]);
    const float omb  = 1.f - beta;
    const float oma1 = 1.f - a1;
    const float obb  = omb * b1[hidx];
    float dcur = 0.f, mem1 = 0.f, pk = -1.f;

    const float4* xr4 = reinterpret_cast<const float4*>(x + (size_t)b * T_STEPS * N_IN);

    // ---- prologue: chunk 0 -> xbf[0]; chunk 1 -> gx regs ----
    float4 gx0, gx1;
    if (tid < 160) {
#pragma unroll
        for (int mm = 0; mm < 2; ++mm) {
            int m = tid + 160 * mm;                  // float4 index in chunk
            float4 v = xr4[m];
            int t = m >> 3, k = (m & 7) * 4;
            u64 p = (u64)f2bf(v.x) | ((u64)f2bf(v.y) << 16)
                  | ((u64)f2bf(v.z) << 32) | ((u64)f2bf(v.w) << 48);
            *(u64*)&xbf[0][t * XROW + k] = p;
        }
        gx0 = xr4[XS_F4 + tid];
        gx1 = xr4[XS_F4 + tid + 160];
    }
    { int t = 40 + (tid >> 5), k = tid & 31; xbf[0][t * XROW + k] = 0; }  // zero pad rows
    __syncthreads();

#pragma unroll 1
    for (int c = 0; c < NCHUNK; ++c) {
        const int cb = c & 1, nb = cb ^ 1;

        // stage chunk c+1 (regs -> bf16 LDS) and zero its pad rows
        if (c + 1 < NCHUNK) {
            if (tid < 160) {
                float4 vv[2] = {gx0, gx1};
#pragma unroll
                for (int mm = 0; mm < 2; ++mm) {
                    int m = tid + 160 * mm;
                    float4 v = vv[mm];
                    int t = m >> 3, k = (m & 7) * 4;
                    u64 p = (u64)f2bf(v.x) | ((u64)f2bf(v.y) << 16)
                          | ((u64)f2bf(v.z) << 32) | ((u64)f2bf(v.w) << 48);
                    *(u64*)&xbf[nb][t * XROW + k] = p;
                }
            }
            int t = 40 + (tid >> 5), k = tid & 31; xbf[nb][t * XROW + k] = 0;
        }
        // prefetch chunk c+2 globals
        if (c + 2 < NCHUNK && tid < 160) {
            gx0 = xr4[(size_t)(c + 2) * XS_F4 + tid];
            gx1 = xr4[(size_t)(c + 2) * XS_F4 + tid + 160];
        }

        // ---- GEMM: cur^T tiles via MFMA ----
        {
            const u16* xb = &xbf[cb][0];
            s16x8 bf[3];
#pragma unroll
            for (int tt = 0; tt < 3; ++tt) {
                int t  = tt * 16 + (lane & 15);
                int k0 = (lane >> 4) * 8;
                bf[tt] = *(const s16x8*)&xb[t * XROW + k0];
            }
#pragma unroll
            for (int i = 0; i < 4; ++i) {
                if (i < ntile) {
                    const int tile = wid + 4 * i;
                    const int hb   = tile * 16 + (lane >> 4) * 4;
#pragma unroll
                    for (int tt = 0; tt < 3; ++tt) {
                        f32x4 acc = {0.f, 0.f, 0.f, 0.f};
                        acc = __builtin_amdgcn_mfma_f32_16x16x32_bf16(af[i], bf[tt], acc, 0, 0, 0);
                        int t = tt * 16 + (lane & 15);
                        *(f32x4*)&curL[t * CURST + hb] = acc;
                    }
                }
            }
        }
        __syncthreads();   // curL ready; staging writes also done

        // ---- one-time MFMA layout self-check (chunk 0) ----
        if (c == 0 && tid < N_HID) {
            int t = tid % CHUNK;
            float exp_ = 0.f;
#pragma unroll
            for (int k = 0; k < N_IN; ++k) {
                size_t o = (size_t)tid * FAN_IN + k;
                exp_ += bf2f(f2bf(W1[o] * mask[o])) * bf2f(xbf[0][t * XROW + k]);
            }
            float got = curL[t * CURST + tid];
            if (fabsf(exp_ - got) > 0.05f) atomicOr(&bad[b], 1);
        }

        // ---- scan: 2-FMA/step recurrence over this chunk ----
#pragma unroll
        for (int s = 0; s < CHUNK; ++s) {
            float cv = curL[s * CURST + hidx];
            dcur = fmaf(beta, dcur, fmaf(omb, cv, obb));
            mem1 = fmaf(a1, mem1, oma1 * dcur);
            pk   = fmaxf(pk, mem1);
        }
        __syncthreads();   // scan done; curL free for next chunk
    }

    if (pk > THRD) atomicOr(&dirty[b], 1);
}

// ============================ K3: emit ============================
// Clean batch: spikes provably zero -> mem2 recursion depends only on b2 (exact).
// Dirty/bad batch: exact single-wave resimulation (round-2 validated structure).

#define NSLOT 4

#define LOADXE(DST, BUF, S)                                                       \
    {                                                                             \
        const float4* xp4_ = reinterpret_cast<const float4*>(&xs[BUF][(S) * N_IN]); \
        _Pragma("unroll")                                                         \
        for (int q_ = 0; q_ < 8; ++q_) {                                          \
            float4 v_ = xp4_[q_];                                                 \
            DST[4*q_+0] = v_.x; DST[4*q_+1] = v_.y;                               \
            DST[4*q_+2] = v_.z; DST[4*q_+3] = v_.w;                               \
        }                                                                         \
    }

#define STEPE(XV)                                                                 \
    {                                                                             \
        float cur[NSLOT];                                                         \
        _Pragma("unroll")                                                         \
        for (int s_ = 0; s_ < NSLOT; ++s_) {                                      \
            float c0 = biasE[s_], c1 = 0.f, c2 = 0.f, c3 = 0.f;                   \
            _Pragma("unroll")                                                     \
            for (int j_ = 0; j_ < N_IN; j_ += 4) {                                \
                c0 = fmaf(XV[j_ + 0], wxE[s_][j_ + 0], c0);                       \
                c1 = fmaf(XV[j_ + 1], wxE[s_][j_ + 1], c1);                       \
                c2 = fmaf(XV[j_ + 2], wxE[s_][j_ + 2], c2);                       \
                c3 = fmaf(XV[j_ + 3], wxE[s_][j_ + 3], c3);                       \
            }                                                                     \
            cur[s_] = (c0 + c1) + (c2 + c3);                                      \
        }                                                                         \
        if (sm0 | sm1 | sm2 | sm3) {                                              \
            unsigned long long mm_[NSLOT] = {sm0, sm1, sm2, sm3};                 \
            _Pragma("unroll")                                                     \
            for (int ss_ = 0; ss_ < NSLOT; ++ss_) {                               \
                unsigned long long m_ = mm_[ss_];                                 \
                while (m_) {                                                      \
                    int j_ = (ss_ << 6) + __builtin_ctzll(m_);                    \
                    m_ &= m_ - 1;                                                 \
                    _Pragma("unroll")                                             \
                    for (int s_ = 0; s_ < NSLOT; ++s_) {                          \
                        size_t o_ = (size_t)hcE[s_] * FAN_IN + N_IN + j_;         \
                        cur[s_] += W1[o_] * mask[o_];                             \
                    }                                                             \
                }                                                                 \
            }                                                                     \
        }                                                                         \
        _Pragma("unroll")                                                         \
        for (int s_ = 0; s_ < NSLOT; ++s_) {                                      \
            dcurE[s_] = fmaf(betaE[s_], dcurE[s_], ombE[s_] * cur[s_]);           \
            mem1E[s_] = fmaf(a1E[s_], mem1E[s_], fmaf(oma1E[s_], dcurE[s_], -sprevE[s_])); \
            sprevE[s_] = (mem1E[s_] > 1.0f) ? 1.0f : 0.0f;                        \
        }                                                                         \
        sm0 = __ballot(mem1E[0] > 1.0f);                                          \
        sm1 = __ballot(mem1E[1] > 1.0f);                                          \
        sm2 = __ballot(mem1E[2] > 1.0f);                                          \
        sm3 = __ballot(mem1E[3] > 1.0f) & 0xFFull;                                \
    }

#define READE(TCUR)                                                               \
    {                                                                             \
        if (lane < N_OUT) {                                                       \
            float r_ = b2v;                                                       \
            unsigned long long mm_[NSLOT] = {sm0, sm1, sm2, sm3};                 \
            _Pragma("unroll")                                                     \
            for (int ss_ = 0; ss_ < NSLOT; ++ss_) {                               \
                unsigned long long m_ = mm_[ss_];                                 \
                while (m_) {                                                      \
                    int j_ = (ss_ << 6) + __builtin_ctzll(m_);                    \
                    m_ &= m_ - 1;                                                 \
                    r_ += W2L[lane * N_HID + j_];                                 \
                }                                                                 \
            }                                                                     \
            mem2 = fmaf(a2, mem2, oma2 * r_);                                     \
            if ((TCUR) > 0) acc += mem2;                                          \
        }                                                                         \
    }

__global__ __launch_bounds__(64, 1) void k3_emit(
    const float* __restrict__ x, const float* __restrict__ W1,
    const float* __restrict__ b1, const float* __restrict__ tau_n,
    const float* __restrict__ tau_m1, const float* __restrict__ W2,
    const float* __restrict__ b2, const float* __restrict__ tau_m2,
    const float* __restrict__ mask, const int* __restrict__ dirty,
    const int* __restrict__ bad, float* __restrict__ out)
{
    const int b = blockIdx.x, lane = threadIdx.x;
    __shared__ float W2L[N_OUT * N_HID];
    __shared__ float xs[2][XS_FLOATS];

    if ((dirty[b] | bad[b]) == 0) {
        // Provably spike-free: mem2(t) = a2*mem2 + (1-a2)*b2, exact.
        if (lane < N_OUT) {
            const float a2   = sigmoidf_(tau_m2[lane]);
            const float oma2 = 1.f - a2;
            const float obr  = oma2 * b2[lane];
            float mem2 = obr, acc = 0.f;   // after step t=0
#pragma unroll 8
            for (int t = 1; t < T_STEPS; ++t) { mem2 = fmaf(a2, mem2, obr); acc += mem2; }
            out[(size_t)b * N_OUT + lane] = acc / (float)T_STEPS;
        }
        return;
    }

    // ---------- exact resimulation (cold path) ----------
    for (int i = lane; i < N_OUT * N_HID; i += 64) W2L[i] = W2[i];

    int hcE[NSLOT];
    float wxE[NSLOT][N_IN];
    float biasE[NSLOT], betaE[NSLOT], a1E[NSLOT], ombE[NSLOT], oma1E[NSLOT];
#pragma unroll
    for (int s = 0; s < NSLOT; ++s) {
        int hh = s * 64 + lane;
        hcE[s] = (hh < N_HID) ? hh : (N_HID - 1);
        const float* wr = W1  + (size_t)hcE[s] * FAN_IN;
        const float* mr = mask + (size_t)hcE[s] * FAN_IN;
#pragma unroll
        for (int j = 0; j < N_IN; ++j) wxE[s][j] = wr[j] * mr[j];
        biasE[s] = b1[hcE[s]];
        betaE[s] = sigmoidf_(tau_n[hcE[s]]);
        a1E[s]   = sigmoidf_(tau_m1[hcE[s]]);
        ombE[s]  = 1.f - betaE[s];
        oma1E[s] = 1.f - a1E[s];
    }

    float dcurE[NSLOT]  = {0.f, 0.f, 0.f, 0.f};
    float mem1E[NSLOT]  = {0.f, 0.f, 0.f, 0.f};
    float sprevE[NSLOT] = {0.f, 0.f, 0.f, 0.f};
    unsigned long long sm0 = 0, sm1 = 0, sm2 = 0, sm3 = 0;

    const int lo_ = (lane < N_OUT) ? lane : 0;
    const float a2   = sigmoidf_(tau_m2[lo_]);
    const float oma2 = 1.f - a2;
    const float b2v  = b2[lo_];
    float mem2 = 0.f, acc = 0.f;

    const float4* xr4 = reinterpret_cast<const float4*>(x + (size_t)b * T_STEPS * N_IN);

    {
        float4* d4 = reinterpret_cast<float4*>(&xs[0][0]);
#pragma unroll
        for (int k = 0; k < 5; ++k) d4[lane + 64 * k] = xr4[lane + 64 * k];
    }
    float4 gx[5];
#pragma unroll
    for (int k = 0; k < 5; ++k) gx[k] = xr4[XS_F4 + lane + 64 * k];

    float xa[N_IN], xb[N_IN];
    LOADXE(xa, 0, 0)

    int tb = 0;
#pragma unroll 1
    for (int c = 0; c < NCHUNK; ++c) {
        const int buf = c & 1;
#pragma unroll 1
        for (int s = 0; s < CHUNK - 2; s += 2) {
            STEPE(xa) LOADXE(xb, buf, s + 1) READE(tb + s)
            STEPE(xb) LOADXE(xa, buf, s + 2) READE(tb + s + 1)
        }
        STEPE(xa) LOADXE(xb, buf, CHUNK - 1) READE(tb + CHUNK - 2)
        STEPE(xb)
        if (c + 1 < NCHUNK) {
            float4* d4 = reinterpret_cast<float4*>(&xs[buf ^ 1][0]);
#pragma unroll
            for (int k = 0; k < 5; ++k) d4[lane + 64 * k] = gx[k];
        }
        if (c + 2 < NCHUNK) {
#pragma unroll
            for (int k = 0; k < 5; ++k)
                gx[k] = xr4[(size_t)(c + 2) * XS_F4 + lane + 64 * k];
        }
        READE(tb + CHUNK - 1)
        if (c + 1 < NCHUNK) LOADXE(xa, buf ^ 1, 0)
        tb += CHUNK;
    }

    if (lane < N_OUT) out[(size_t)b * N_OUT + lane] = acc / (float)T_STEPS;
}

extern "C" void kernel_launch(void* const* d_in, const int* in_sizes, int n_in,
                              void* d_out, int out_size, void* d_ws, size_t ws_size,
                              hipStream_t stream) {
    const float* x      = (const float*)d_in[0];
    const float* W1     = (const float*)d_in[1];
    const float* b1     = (const float*)d_in[2];
    const float* tau_n  = (const float*)d_in[3];
    const float* tau_m1 = (const float*)d_in[4];
    const float* W2     = (const float*)d_in[5];
    const float* b2     = (const float*)d_in[6];
    const float* tau_m2 = (const float*)d_in[7];
    const float* mask   = (const float*)d_in[8];
    float* out = (float*)d_out;

    const int B = in_sizes[0] / (T_STEPS * N_IN);  // 512
    int* dirty = (int*)d_ws;
    int* bad   = ((int*)d_ws) + B;

    hipLaunchKernelGGL(k1_scan, dim3(B), dim3(256), 0, stream,
                       x, W1, b1, tau_n, tau_m1, mask, dirty, bad);
    hipLaunchKernelGGL(k3_emit, dim3(B), dim3(64), 0, stream,
                       x, W1, b1, tau_n, tau_m1, W2, b2, tau_m2, mask, dirty, bad, out);
}

// Round 12
// 233.461 us; speedup vs baseline: 8.1149x; 1.1736x over previous
//
#include <hip/hip_runtime.h>
#include <cstdint>
#include <cstddef>

#define N_IN    32
#define N_HID   200
#define N_OUT   3
#define FAN_IN  232   // N_IN + N_HID
#define T_STEPS 2000
#define CHUNK   40                    // timesteps per chunk
#define NCHUNK  (T_STEPS / CHUNK)     // 50, exact
#define TPAD    48                    // staged x rows (3 t-tiles of 16)
#define XROW    40                    // u16 stride of xbf rows
#define TROW    52                    // f32 stride of curL rows [h][t] (16B-aligned, 2-way banks)
#define NHT     208                   // padded h (13 tiles of 16)
#define XS_FLOATS (CHUNK * N_IN)      // 1280
#define XS_F4     (XS_FLOATS / 4)     // 320 float4 per chunk
#define THRD    0.90f                 // dirty threshold (VTH=1.0; mem1 max ~0.2; bf16 err ~1e-3)

typedef float  f32x4 __attribute__((ext_vector_type(4)));
typedef short  s16x8 __attribute__((ext_vector_type(8)));
typedef unsigned short u16;
typedef unsigned long long u64;

__device__ __forceinline__ float sigmoidf_(float v) { return 1.0f / (1.0f + expf(-v)); }

__device__ __forceinline__ u16 f2bf(float f) {     // fp32 -> bf16 RNE
    union { float f; unsigned u; } v; v.f = f;
    unsigned r = v.u + 0x7FFFu + ((v.u >> 16) & 1u);
    return (u16)(r >> 16);
}
__device__ __forceinline__ float bf2f(u16 h) {
    union { float f; unsigned u; } v; v.u = ((unsigned)h) << 16; return v.f;
}
__device__ __forceinline__ unsigned cvtpk(float lo, float hi) {   // 2x f32 -> packed bf16
    unsigned r; asm("v_cvt_pk_bf16_f32 %0, %1, %2" : "=v"(r) : "v"(lo), "v"(hi)); return r;
}

// pack one float4 (chunk-linear index M) into bf16 LDS row [t][k]
#define STAGE4(BUF, M, V)                                                         \
    {                                                                             \
        int t_ = (M) >> 3, k_ = ((M) & 7) * 4;                                    \
        u64 p_ = (u64)cvtpk((V).x, (V).y) | ((u64)cvtpk((V).z, (V).w) << 32);     \
        *(u64*)&xbf[BUF][t_ * XROW + k_] = p_;                                    \
    }

// ============================ K1: MFMA verify-scan + clean emit ============================
// GEMM D = X·W^T per chunk (D[t][h]: each lane holds 4 consecutive t of one h ->
// b128 writes to [h][t] curL; scan reads b128). Zero-spike mem1 recurrence per
// neuron; flags block if mem1 approaches VTH. Clean blocks: closed-form output.

__global__ __launch_bounds__(256, 2) void k1_scan(
    const float* __restrict__ x, const float* __restrict__ W1,
    const float* __restrict__ b1, const float* __restrict__ tau_n,
    const float* __restrict__ tau_m1, const float* __restrict__ b2,
    const float* __restrict__ tau_m2, const float* __restrict__ mask,
    int* __restrict__ flag, float* __restrict__ out)
{
    const int b    = blockIdx.x;
    const int tid  = threadIdx.x;
    const int wid  = tid >> 6;
    const int lane = tid & 63;

    __shared__ u16   xbf[2][TPAD * XROW];   // 7.5 KB (bf16 X chunks, double-buffered)
    __shared__ float curL[NHT * TROW];      // 43.3 KB, [h][t]
    __shared__ int   sflag;

    if (tid == 0) sflag = 0;

    // ---- W fragments (B operand): wave w owns h-tiles {w, w+4, w+8, (12 if w==0)} ----
    const int ntile = (wid == 0) ? 4 : 3;
    s16x8 wf[4];
#pragma unroll
    for (int i = 0; i < 4; ++i) {
        const int tile = wid + 4 * i;
        const int h    = tile * 16 + (lane & 15);
        const int k0   = (lane >> 4) * 8;
#pragma unroll
        for (int j = 0; j < 8; ++j) {
            float wv = 0.f;
            if (i < ntile && h < N_HID) {
                size_t o = (size_t)h * FAN_IN + k0 + j;
                wv = W1[o] * mask[o];
            }
            wf[i][j] = (short)f2bf(wv);
        }
    }

    // ---- scan parameters (thread = neuron) ----
    const int hidx = (tid < N_HID) ? tid : (N_HID - 1);
    const float beta = sigmoidf_(tau_n[hidx]);
    const float a1   = sigmoidf_(tau_m1[hidx]);
    const float omb  = 1.f - beta;
    const float oma1 = 1.f - a1;
    const float obb  = omb * b1[hidx];
    float dcur = 0.f, mem1 = 0.f, pk = -1.f;

    const float4* xr4 = reinterpret_cast<const float4*>(x + (size_t)b * T_STEPS * N_IN);

    // ---- prologue: chunk 0 -> xbf[0]; chunk 1 -> gx regs; zero pad rows of both buffers ----
    float4 gx0, gx1;
    if (tid < 160) {
        float4 v0 = xr4[tid], v1 = xr4[tid + 160];
        STAGE4(0, tid, v0)
        STAGE4(0, tid + 160, v1)
        gx0 = xr4[XS_F4 + tid];
        gx1 = xr4[XS_F4 + tid + 160];
    }
    { int t = 40 + (tid >> 5), k = tid & 31; xbf[0][t * XROW + k] = 0; xbf[1][t * XROW + k] = 0; }
    __syncthreads();

#pragma unroll 1
    for (int c = 0; c < NCHUNK; ++c) {
        const int cb = c & 1, nb = cb ^ 1;

        // stage chunk c+1 (regs -> bf16 LDS)
        if (c + 1 < NCHUNK && tid < 160) {
            STAGE4(nb, tid, gx0)
            STAGE4(nb, tid + 160, gx1)
        }
        // prefetch chunk c+2 globals
        if (c + 2 < NCHUNK && tid < 160) {
            gx0 = xr4[(size_t)(c + 2) * XS_F4 + tid];
            gx1 = xr4[(size_t)(c + 2) * XS_F4 + tid + 160];
        }

        // ---- GEMM: D[t][h] tiles via MFMA (A = x, B = W^T) ----
        {
            const u16* xb = &xbf[cb][0];
            s16x8 xf[3];
#pragma unroll
            for (int tt = 0; tt < 3; ++tt) {
                int t  = tt * 16 + (lane & 15);
                int k0 = (lane >> 4) * 8;
                xf[tt] = *(const s16x8*)&xb[t * XROW + k0];
            }
#pragma unroll
            for (int i = 0; i < 4; ++i) {
                if (i < ntile) {
                    const int hb = (wid + 4 * i) * 16 + (lane & 15);   // this lane's h
                    const int tg = (lane >> 4) * 4;                    // t sub-block
#pragma unroll
                    for (int tt = 0; tt < 3; ++tt) {
                        f32x4 acc = {0.f, 0.f, 0.f, 0.f};
                        acc = __builtin_amdgcn_mfma_f32_16x16x32_bf16(xf[tt], wf[i], acc, 0, 0, 0);
                        *(f32x4*)&curL[hb * TROW + tt * 16 + tg] = acc;
                    }
                }
            }
        }
        __syncthreads();   // curL ready; staging writes done

        // ---- one-time MFMA layout self-check (chunk 0) ----
        if (c == 0 && tid < N_HID) {
            int t = tid % CHUNK;
            float exp_ = 0.f;
#pragma unroll
            for (int k = 0; k < N_IN; ++k) {
                size_t o = (size_t)tid * FAN_IN + k;
                exp_ += bf2f(f2bf(W1[o] * mask[o])) * bf2f(xbf[0][t * XROW + k]);
            }
            float got = curL[tid * TROW + t];
            if (fabsf(exp_ - got) > 0.05f) atomicOr(&sflag, 1);
        }

        // ---- scan: 2-FMA/step recurrence, b128 reads ----
#pragma unroll
        for (int s4 = 0; s4 < CHUNK / 4; ++s4) {
            f32x4 c4 = *(const f32x4*)&curL[hidx * TROW + s4 * 4];
#pragma unroll
            for (int r = 0; r < 4; ++r) {
                dcur = fmaf(beta, dcur, fmaf(omb, c4[r], obb));
                mem1 = fmaf(a1, mem1, oma1 * dcur);
                pk   = fmaxf(pk, mem1);
            }
        }
        __syncthreads();   // scan done; curL free for next chunk
    }

    if (pk > THRD) atomicOr(&sflag, 1);
    __syncthreads();
    const int f = sflag;
    if (tid == 0) flag[b] = f;
    if (f == 0 && tid < N_OUT) {
        // Provably spike-free: closed-form leaky-integrator average.
        // m_t = obr*(1-a2^{t+1})/(1-a2); out = sum_{t=1..1999} m_t / 2000
        double a2d = 1.0 / (1.0 + exp(-(double)tau_m2[tid]));
        double v   = (double)b2[tid] * (1999.0 - a2d * a2d / (1.0 - a2d)) / 2000.0;
        out[(size_t)b * N_OUT + tid] = (float)v;
    }
}

// ============================ K3: exact resim for flagged blocks ============================

#define NSLOT 4

#define LOADXE(DST, BUF, S)                                                       \
    {                                                                             \
        const float4* xp4_ = reinterpret_cast<const float4*>(&xs[BUF][(S) * N_IN]); \
        _Pragma("unroll")                                                         \
        for (int q_ = 0; q_ < 8; ++q_) {                                          \
            float4 v_ = xp4_[q_];                                                 \
            DST[4*q_+0] = v_.x; DST[4*q_+1] = v_.y;                               \
            DST[4*q_+2] = v_.z; DST[4*q_+3] = v_.w;                               \
        }                                                                         \
    }

#define STEPE(XV)                                                                 \
    {                                                                             \
        float cur[NSLOT];                                                         \
        _Pragma("unroll")                                                         \
        for (int s_ = 0; s_ < NSLOT; ++s_) {                                      \
            float c0 = biasE[s_], c1 = 0.f, c2 = 0.f, c3 = 0.f;                   \
            _Pragma("unroll")                                                     \
            for (int j_ = 0; j_ < N_IN; j_ += 4) {                                \
                c0 = fmaf(XV[j_ + 0], wxE[s_][j_ + 0], c0);                       \
                c1 = fmaf(XV[j_ + 1], wxE[s_][j_ + 1], c1);                       \
                c2 = fmaf(XV[j_ + 2], wxE[s_][j_ + 2], c2);                       \
                c3 = fmaf(XV[j_ + 3], wxE[s_][j_ + 3], c3);                       \
            }                                                                     \
            cur[s_] = (c0 + c1) + (c2 + c3);                                      \
        }                                                                         \
        if (sm0 | sm1 | sm2 | sm3) {                                              \
            unsigned long long mm_[NSLOT] = {sm0, sm1, sm2, sm3};                 \
            _Pragma("unroll")                                                     \
            for (int ss_ = 0; ss_ < NSLOT; ++ss_) {                               \
                unsigned long long m_ = mm_[ss_];                                 \
                while (m_) {                                                      \
                    int j_ = (ss_ << 6) + __builtin_ctzll(m_);                    \
                    m_ &= m_ - 1;                                                 \
                    _Pragma("unroll")                                             \
                    for (int s_ = 0; s_ < NSLOT; ++s_) {                          \
                        size_t o_ = (size_t)hcE[s_] * FAN_IN + N_IN + j_;         \
                        cur[s_] += W1[o_] * mask[o_];                             \
                    }                                                             \
                }                                                                 \
            }                                                                     \
        }                                                                         \
        _Pragma("unroll")                                                         \
        for (int s_ = 0; s_ < NSLOT; ++s_) {                                      \
            dcurE[s_] = fmaf(betaE[s_], dcurE[s_], ombE[s_] * cur[s_]);           \
            mem1E[s_] = fmaf(a1E[s_], mem1E[s_], fmaf(oma1E[s_], dcurE[s_], -sprevE[s_])); \
            sprevE[s_] = (mem1E[s_] > 1.0f) ? 1.0f : 0.0f;                        \
        }                                                                         \
        sm0 = __ballot(mem1E[0] > 1.0f);                                          \
        sm1 = __ballot(mem1E[1] > 1.0f);                                          \
        sm2 = __ballot(mem1E[2] > 1.0f);                                          \
        sm3 = __ballot(mem1E[3] > 1.0f) & 0xFFull;                                \
    }

#define READE(TCUR)                                                               \
    {                                                                             \
        if (lane < N_OUT) {                                                       \
            float r_ = b2v;                                                       \
            unsigned long long mm_[NSLOT] = {sm0, sm1, sm2, sm3};                 \
            _Pragma("unroll")                                                     \
            for (int ss_ = 0; ss_ < NSLOT; ++ss_) {                               \
                unsigned long long m_ = mm_[ss_];                                 \
                while (m_) {                                                      \
                    int j_ = (ss_ << 6) + __builtin_ctzll(m_);                    \
                    m_ &= m_ - 1;                                                 \
                    r_ += W2L[lane * N_HID + j_];                                 \
                }                                                                 \
            }                                                                     \
            mem2 = fmaf(a2, mem2, oma2 * r_);                                     \
            if ((TCUR) > 0) acc += mem2;                                          \
        }                                                                         \
    }

__global__ __launch_bounds__(64, 1) void k3_emit(
    const float* __restrict__ x, const float* __restrict__ W1,
    const float* __restrict__ b1, const float* __restrict__ tau_n,
    const float* __restrict__ tau_m1, const float* __restrict__ W2,
    const float* __restrict__ b2, const float* __restrict__ tau_m2,
    const float* __restrict__ mask, const int* __restrict__ flag,
    float* __restrict__ out)
{
    const int b = blockIdx.x, lane = threadIdx.x;
    __shared__ float W2L[N_OUT * N_HID];
    __shared__ float xs[2][XS_FLOATS];

    if (flag[b] == 0) return;   // clean: k1 already emitted the output

    // ---------- exact resimulation (cold path; round-2-validated) ----------
    for (int i = lane; i < N_OUT * N_HID; i += 64) W2L[i] = W2[i];

    int hcE[NSLOT];
    float wxE[NSLOT][N_IN];
    float biasE[NSLOT], betaE[NSLOT], a1E[NSLOT], ombE[NSLOT], oma1E[NSLOT];
#pragma unroll
    for (int s = 0; s < NSLOT; ++s) {
        int hh = s * 64 + lane;
        hcE[s] = (hh < N_HID) ? hh : (N_HID - 1);
        const float* wr = W1  + (size_t)hcE[s] * FAN_IN;
        const float* mr = mask + (size_t)hcE[s] * FAN_IN;
#pragma unroll
        for (int j = 0; j < N_IN; ++j) wxE[s][j] = wr[j] * mr[j];
        biasE[s] = b1[hcE[s]];
        betaE[s] = sigmoidf_(tau_n[hcE[s]]);
        a1E[s]   = sigmoidf_(tau_m1[hcE[s]]);
        ombE[s]  = 1.f - betaE[s];
        oma1E[s] = 1.f - a1E[s];
    }

    float dcurE[NSLOT]  = {0.f, 0.f, 0.f, 0.f};
    float mem1E[NSLOT]  = {0.f, 0.f, 0.f, 0.f};
    float sprevE[NSLOT] = {0.f, 0.f, 0.f, 0.f};
    unsigned long long sm0 = 0, sm1 = 0, sm2 = 0, sm3 = 0;

    const int lo_ = (lane < N_OUT) ? lane : 0;
    const float a2   = sigmoidf_(tau_m2[lo_]);
    const float oma2 = 1.f - a2;
    const float b2v  = b2[lo_];
    float mem2 = 0.f, acc = 0.f;

    const float4* xr4 = reinterpret_cast<const float4*>(x + (size_t)b * T_STEPS * N_IN);

    {
        float4* d4 = reinterpret_cast<float4*>(&xs[0][0]);
#pragma unroll
        for (int k = 0; k < 5; ++k) d4[lane + 64 * k] = xr4[lane + 64 * k];
    }
    float4 gx[5];
#pragma unroll
    for (int k = 0; k < 5; ++k) gx[k] = xr4[XS_F4 + lane + 64 * k];

    float xa[N_IN], xb[N_IN];
    LOADXE(xa, 0, 0)

    int tb = 0;
#pragma unroll 1
    for (int c = 0; c < NCHUNK; ++c) {
        const int buf = c & 1;
#pragma unroll 1
        for (int s = 0; s < CHUNK - 2; s += 2) {
            STEPE(xa) LOADXE(xb, buf, s + 1) READE(tb + s)
            STEPE(xb) LOADXE(xa, buf, s + 2) READE(tb + s + 1)
        }
        STEPE(xa) LOADXE(xb, buf, CHUNK - 1) READE(tb + CHUNK - 2)
        STEPE(xb)
        if (c + 1 < NCHUNK) {
            float4* d4 = reinterpret_cast<float4*>(&xs[buf ^ 1][0]);
#pragma unroll
            for (int k = 0; k < 5; ++k) d4[lane + 64 * k] = gx[k];
        }
        if (c + 2 < NCHUNK) {
#pragma unroll
            for (int k = 0; k < 5; ++k)
                gx[k] = xr4[(size_t)(c + 2) * XS_F4 + lane + 64 * k];
        }
        READE(tb + CHUNK - 1)
        if (c + 1 < NCHUNK) LOADXE(xa, buf ^ 1, 0)
        tb += CHUNK;
    }

    if (lane < N_OUT) out[(size_t)b * N_OUT + lane] = acc / (float)T_STEPS;
}

extern "C" void kernel_launch(void* const* d_in, const int* in_sizes, int n_in,
                              void* d_out, int out_size, void* d_ws, size_t ws_size,
                              hipStream_t stream) {
    const float* x      = (const float*)d_in[0];
    const float* W1     = (const float*)d_in[1];
    const float* b1     = (const float*)d_in[2];
    const float* tau_n  = (const float*)d_in[3];
    const float* tau_m1 = (const float*)d_in[4];
    const float* W2     = (const float*)d_in[5];
    const float* b2     = (const float*)d_in[6];
    const float* tau_m2 = (const float*)d_in[7];
    const float* mask   = (const float*)d_in[8];
    float* out  = (float*)d_out;
    int*   flag = (int*)d_ws;

    const int B = in_sizes[0] / (T_STEPS * N_IN);  // 512

    hipLaunchKernelGGL(k1_scan, dim3(B), dim3(256), 0, stream,
                       x, W1, b1, tau_n, tau_m1, b2, tau_m2, mask, flag, out);
    hipLaunchKernelGGL(k3_emit, dim3(B), dim3(64), 0, stream,
                       x, W1, b1, tau_n, tau_m1, W2, b2, tau_m2, mask, flag, out);
}